// Round 19
// baseline (262.222 us; speedup 1.0000x reference)
//
#include <hip/hip_runtime.h>
#include <hip/hip_bf16.h>

typedef __attribute__((ext_vector_type(4))) float f32x4;
typedef __attribute__((ext_vector_type(16))) float f32x16;
typedef __attribute__((ext_vector_type(2))) unsigned int u32x2;
typedef __attribute__((ext_vector_type(4))) unsigned int u32x4;
typedef __attribute__((ext_vector_type(8))) __bf16 bf16x8;

__device__ inline unsigned short f2bf(float x) {
    return __builtin_bit_cast(unsigned short, (__bf16)x);
}
__device__ inline unsigned int pack2(float lo, float hi) {
    return (unsigned int)f2bf(lo) | ((unsigned int)f2bf(hi) << 16);
}
__device__ inline u32x4 cvt8(const float* __restrict__ p) {
    f32x4 a = *(const f32x4*)p;
    f32x4 b = *(const f32x4*)(p + 4);
    u32x4 r;
    r[0] = pack2(a[0], a[1]);
    r[1] = pack2(a[2], a[3]);
    r[2] = pack2(b[0], b[1]);
    r[3] = pack2(b[2], b[3]);
    return r;
}
__device__ inline bf16x8 ldfrag(const unsigned short* p) {
    u32x4 t = *(const u32x4*)p;
    return __builtin_bit_cast(bf16x8, t);
}

// ---------------- fp32 -> bf16 weight converters, SLOT-SWIZZLED ----------
__global__ __launch_bounds__(256) void cvt_w3(
    const float* __restrict__ wq, const float* __restrict__ wk,
    const float* __restrict__ wv, unsigned short* __restrict__ dst)
{
    const float* s = blockIdx.y == 0 ? wq : (blockIdx.y == 1 ? wk : wv);
    unsigned short* d = dst + (size_t)blockIdx.y * 1048576;
    const int i = blockIdx.x * 256 + threadIdx.x;
    const int n = i >> 7;
    const int kg = (i >> 2) & 31;
    const int slot = (i & 3) ^ ((n >> 1) & 3);
    *(u32x4*)(d + (((size_t)n << 10) | (kg << 5) | (slot << 3))) =
        cvt8(s + (size_t)i * 8);
}
__global__ __launch_bounds__(256) void cvt_w1(
    const float* __restrict__ src, unsigned short* __restrict__ dst)
{
    const int i = blockIdx.x * 256 + threadIdx.x;
    const int n = i >> 7;
    const int kg = (i >> 2) & 31;
    const int slot = (i & 3) ^ ((n >> 1) & 3);
    *(u32x4*)(dst + (((size_t)n << 10) | (kg << 5) | (slot << 3))) =
        cvt8(src + (size_t)i * 8);
}

// ---------------- Fused QKV projection GEMM ----------------
// r19: block tile 128x256, 4 waves 2x2, wave tile 64x128 -> 12 b128 frag
// reads feed 32 MFMA = 42.7K FLOP/KB (+33% LDS intensity vs r17's 64x64).
// Theory: kernel is LDS-read-throughput-bound (r17 vs r18 isolated intensity,
// not occupancy, as the perf-tracking variable). Grid (64,4,3) z slowest;
// A re-read x8 -> x4. Distance-2 A reg-prefetch (depth proven null r14/r17),
// acc 128 regs -> ~200 unified, 2 waves/SIMD (same as r17: isolates intensity).
__global__ __launch_bounds__(256) void gemm_qkv(
    const float* __restrict__ Aq, const float* __restrict__ Ak,
    const float* __restrict__ Av, const unsigned short* __restrict__ W16,
    const float* __restrict__ bq, const float* __restrict__ bk,
    const float* __restrict__ bv, unsigned short* __restrict__ Qb,
    unsigned short* __restrict__ Kb, unsigned short* __restrict__ Vtb,
    float qscale)
{
    __shared__ unsigned short Al[2][128][40];
    __shared__ unsigned short Bl[2][256][32];
    const int z = blockIdx.z;
    const float* Ap = z == 0 ? Aq : (z == 1 ? Ak : Av);
    const unsigned short* Bw = W16 + (size_t)z * 1048576;
    const float* bias = z == 0 ? bq : (z == 1 ? bk : bv);
    const float alpha = z == 0 ? qscale : 1.0f;

    const int tid = threadIdx.x;
    const int lane = tid & 63, w = tid >> 6;
    const int wr = w >> 1, wc = w & 1;
    const int m0 = blockIdx.x * 128, n0 = blockIdx.y * 256;
    const int fr = lane & 15, fq = lane >> 4;
    const int fqs = (fq ^ ((fr >> 1) & 3)) * 8;

    f32x4 acc[4][8] = {};
    f32x4 apA[2][2], apB[2][2];   // distance-2 slots

    auto issueB = [&](int p, int k0) {
        // 256x32 tile = 8192 hw = 16 gll chunks of 1KB; 4 per wave
#pragma unroll
        for (int j = 0; j < 4; ++j) {
            const int f = (w * 4 + j) * 512 + lane * 8;
            const int r = f >> 5, c = f & 31;
            __builtin_amdgcn_global_load_lds(
                (const __attribute__((address_space(1))) void*)(Bw + (size_t)(n0 + r) * 1024 + k0 + c),
                (__attribute__((address_space(3))) void*)(&Bl[p][0][0] + (w * 4 + j) * 512),
                16, 0, 0);
        }
    };
    auto loadA = [&](f32x4 (&ap)[2][2], int k0) {
#pragma unroll
        for (int i = 0; i < 2; ++i) {
            const int e = (i * 256 + tid) * 8;
            const int r = e >> 5, c = e & 31;
            const float* src = Ap + (size_t)(m0 + r) * 1024 + k0 + c;
            ap[i][0] = *(const f32x4*)src;
            ap[i][1] = *(const f32x4*)(src + 4);
        }
    };
    auto stepBody = [&](int k0, f32x4 (&ap)[2][2], int p) {
#pragma unroll
        for (int i = 0; i < 2; ++i) {
            const int e = (i * 256 + tid) * 8;
            const int r = e >> 5, c = e & 31;
            u32x4 v;
            v[0] = pack2(ap[i][0][0], ap[i][0][1]);
            v[1] = pack2(ap[i][0][2], ap[i][0][3]);
            v[2] = pack2(ap[i][1][0], ap[i][1][1]);
            v[3] = pack2(ap[i][1][2], ap[i][1][3]);
            *(u32x4*)&Al[p][r][c] = v;
        }
        __syncthreads();
        if (k0 + 32 < 1024) issueB(p ^ 1, k0 + 32);
        if (k0 + 64 < 1024) loadA(ap, k0 + 64);   // refill, distance-2

        bf16x8 af[4], bfv[8];
#pragma unroll
        for (int mt = 0; mt < 4; ++mt)
            af[mt] = ldfrag(&Al[p][wr * 64 + mt * 16 + fr][8 * fq]);
#pragma unroll
        for (int nt = 0; nt < 8; ++nt)
            bfv[nt] = ldfrag(&Bl[p][wc * 128 + nt * 16 + fr][fqs]);
#pragma unroll
        for (int mt = 0; mt < 4; ++mt)
#pragma unroll
            for (int nt = 0; nt < 8; ++nt)
                acc[mt][nt] = __builtin_amdgcn_mfma_f32_16x16x32_bf16(af[mt], bfv[nt], acc[mt][nt], 0, 0, 0);
    };

    loadA(apA, 0);
    loadA(apB, 32);
    issueB(0, 0);

    for (int k0 = 0; k0 < 1024; k0 += 64) {
        stepBody(k0, apA, 0);
        stepBody(k0 + 32, apB, 1);
    }

#pragma unroll
    for (int mt = 0; mt < 4; ++mt) {
#pragma unroll
        for (int nt = 0; nt < 8; ++nt) {
            const int col = n0 + wc * 128 + nt * 16 + fr;
            const float bb = bias[col];
            const int row0 = m0 + wr * 64 + mt * 16 + fq * 4;
            if (z == 2) {
                float v0 = acc[mt][nt][0] + bb, v1 = acc[mt][nt][1] + bb;
                float v2 = acc[mt][nt][2] + bb, v3 = acc[mt][nt][3] + bb;
                const int bb_ = row0 >> 11, key = row0 & 2047;
                const int key2 = (key & ~12) | ((key & 4) << 1) | ((key & 8) >> 1);
                const int dh = col & 63;
                const int gg = ((dh ^ (dh >> 3)) & 7) << 3;
                const size_t idx = ((size_t)bb_ * 1024 + col) * 2048 + (key2 ^ gg);
                u32x2 pv;
                pv[0] = pack2(v0, v1);
                pv[1] = pack2(v2, v3);
                *(u32x2*)(Vtb + idx) = pv;
            } else if (z == 1) {
#pragma unroll
                for (int r = 0; r < 4; ++r) {
                    const int row = row0 + r;
                    const int tm = row & 127;
                    const int gg = ((tm ^ (tm >> 3)) & 7) << 3;
                    const size_t idx = (size_t)row * 1024 + ((col & ~63) | ((col & 63) ^ gg));
                    Kb[idx] = f2bf(acc[mt][nt][r] + bb);
                }
            } else {
#pragma unroll
                for (int r = 0; r < 4; ++r) {
                    const size_t idx = (size_t)(row0 + r) * 1024 + col;
                    Qb[idx] = f2bf((acc[mt][nt][r] + bb) * alpha);
                }
            }
        }
    }
}

// ---------------- Output-projection GEMM (r15/r17, unchanged) -------
__global__ __launch_bounds__(256) void gemm_out(
    const unsigned short* __restrict__ A, const unsigned short* __restrict__ Bw,
    const float* __restrict__ bias, const float* __restrict__ resid,
    float* __restrict__ Cp)
{
    __shared__ unsigned short Al[2][128][32];
    __shared__ unsigned short Bl[2][128][32];
    const int tid = threadIdx.x;
    const int lane = tid & 63, w = tid >> 6;
    const int wr = w >> 1, wc = w & 1;
    const int m0 = blockIdx.x * 128, n0 = blockIdx.y * 128;
    const int fr = lane & 15, fq = lane >> 4;
    const int fqs = (fq ^ ((fr >> 1) & 3)) * 8;

    f32x4 acc[4][4] = {};

    auto stage = [&](int p, int k0) {
#pragma unroll
        for (int j = 0; j < 2; ++j) {
            const int f = (w * 2 + j) * 512 + lane * 8;
            const int r = f >> 5, c = f & 31;
            __builtin_amdgcn_global_load_lds(
                (const __attribute__((address_space(1))) void*)(A + (size_t)(m0 + r) * 1024 + k0 + c),
                (__attribute__((address_space(3))) void*)(&Al[p][0][0] + (w * 2 + j) * 512),
                16, 0, 0);
            __builtin_amdgcn_global_load_lds(
                (const __attribute__((address_space(1))) void*)(Bw + (size_t)(n0 + r) * 1024 + k0 + c),
                (__attribute__((address_space(3))) void*)(&Bl[p][0][0] + (w * 2 + j) * 512),
                16, 0, 0);
        }
    };

    stage(0, 0);

    for (int k0 = 0; k0 < 1024; k0 += 32) {
        const int p = (k0 >> 5) & 1;
        __syncthreads();
        if (k0 + 32 < 1024) stage(p ^ 1, k0 + 32);

        bf16x8 af[4], bfv[4];
#pragma unroll
        for (int mt = 0; mt < 4; ++mt)
            af[mt] = ldfrag(&Al[p][wr * 64 + mt * 16 + fr][fqs]);
#pragma unroll
        for (int nt = 0; nt < 4; ++nt)
            bfv[nt] = ldfrag(&Bl[p][wc * 64 + nt * 16 + fr][fqs]);
#pragma unroll
        for (int mt = 0; mt < 4; ++mt)
#pragma unroll
            for (int nt = 0; nt < 4; ++nt)
                acc[mt][nt] = __builtin_amdgcn_mfma_f32_16x16x32_bf16(af[mt], bfv[nt], acc[mt][nt], 0, 0, 0);
    }

#pragma unroll
    for (int mt = 0; mt < 4; ++mt) {
#pragma unroll
        for (int nt = 0; nt < 4; ++nt) {
            const int col = n0 + wc * 64 + nt * 16 + fr;
            const float bb = bias[col];
            const int row0 = m0 + wr * 64 + mt * 16 + fq * 4;
#pragma unroll
            for (int r = 0; r < 4; ++r) {
                const size_t idx = (size_t)(row0 + r) * 1024 + col;
                Cp[idx] = acc[mt][nt][r] + bb + resid[idx];
            }
        }
    }
}

// ---------------- Flash attention (r15/r17, unchanged) ----------------
__global__ __launch_bounds__(256, 2) void attn_fwd(
    const unsigned short* __restrict__ K, const unsigned short* __restrict__ Q,
    const unsigned short* __restrict__ Vt_g, const int* __restrict__ mask,
    unsigned short* __restrict__ O)
{
    __shared__ unsigned short Kl[2][128][64];
    __shared__ unsigned short Vl[2][64][128];
    __shared__ unsigned short mlb[2][128];
    const int tid = threadIdx.x, lane = tid & 63, w = tid >> 6;
    const int l31 = lane & 31, hi = lane >> 5;
    const int qb = blockIdx.y >> 3;
    const int bh = ((blockIdx.y & 7) << 3) | blockIdx.x;
    const int q0 = qb * 256;
    const int b = bh >> 4;
    const size_t rowbase = (size_t)b * 2048;
    const int hoff = (bh & 15) * 64;
    const size_t vbase = (size_t)bh * 64 * 2048;

    const u32x4 onesu = {0x3F803F80u, 0x3F803F80u, 0x3F803F80u, 0x3F803F80u};
    const bf16x8 vones = __builtin_bit_cast(bf16x8, onesu);

    bf16x8 aq[2][4];
#pragma unroll
    for (int a = 0; a < 2; ++a) {
        const unsigned short* qp = Q + (rowbase + q0 + w * 64 + a * 32 + l31) * 1024 + hoff + hi * 8;
#pragma unroll
        for (int kk = 0; kk < 4; ++kk) aq[a][kk] = ldfrag(qp + kk * 16);
    }
    f32x16 o[2][2] = {};
    f32x16 os[2] = {};

    auto stageKV = [&](int p, int kb2) {
#pragma unroll
        for (int j = 0; j < 4; ++j) {
            const int q = w * 4 + j;
            const int hK = q * 512 + lane * 8;
            const int rK = hK >> 6, cK = hK & 63;
            __builtin_amdgcn_global_load_lds(
                (const __attribute__((address_space(1))) void*)(K + (rowbase + kb2 + rK) * 1024 + hoff + cK),
                (__attribute__((address_space(3))) void*)(&Kl[p][0][0] + q * 512),
                16, 0, 0);
            const int rV = hK >> 7, cV = hK & 127;
            __builtin_amdgcn_global_load_lds(
                (const __attribute__((address_space(1))) void*)(Vt_g + vbase + (size_t)rV * 2048 + kb2 + cV),
                (__attribute__((address_space(3))) void*)(&Vl[p][0][0] + q * 512),
                16, 0, 0);
        }
    };

    stageKV(0, 0);
    int mpre = (tid < 128) ? mask[rowbase + tid] : 0;
    if (tid < 128) mlb[0][tid] = f2bf(mpre == 0 ? -30000.0f : 0.0f);
    __syncthreads();

    for (int kb = 0, it = 0; kb < 2048; kb += 128, ++it) {
        const int p = it & 1;
        if (kb + 128 < 2048) {
            stageKV(p ^ 1, kb + 128);
            if (tid < 128) mpre = mask[rowbase + kb + 128 + tid];
        }

#pragma unroll
        for (int t = 0; t < 4; ++t) {
            const int swt = ((l31 ^ ((l31 >> 3) + t * 4)) & 7) << 3;
            const unsigned int mv = (hi == 0) ? (unsigned int)mlb[p][t * 32 + l31] : 0u;
            const u32x4 mfu = {mv, 0u, 0u, 0u};
            const bf16x8 kfm = __builtin_bit_cast(bf16x8, mfu);

            f32x16 z0 = {}, z1 = {};
            __builtin_amdgcn_s_setprio(1);
            z0 = __builtin_amdgcn_mfma_f32_32x32x16_bf16(kfm, vones, z0, 0, 0, 0);
            z1 = __builtin_amdgcn_mfma_f32_32x32x16_bf16(kfm, vones, z1, 0, 0, 0);
#pragma unroll
            for (int kk = 0; kk < 4; ++kk) {
                bf16x8 kf = ldfrag(&Kl[p][t * 32 + l31][(kk * 16 + hi * 8) ^ swt]);
                z0 = __builtin_amdgcn_mfma_f32_32x32x16_bf16(kf, aq[0][kk], z0, 0, 0, 0);
                z1 = __builtin_amdgcn_mfma_f32_32x32x16_bf16(kf, aq[1][kk], z1, 0, 0, 0);
            }
            __builtin_amdgcn_s_setprio(0);

            unsigned int pk[2][4][2];
#pragma unroll
            for (int g = 0; g < 4; ++g) {
                {
                    float p0 = __builtin_amdgcn_exp2f(z0[g * 4 + 0]);
                    float p1 = __builtin_amdgcn_exp2f(z0[g * 4 + 1]);
                    float p2 = __builtin_amdgcn_exp2f(z0[g * 4 + 2]);
                    float p3 = __builtin_amdgcn_exp2f(z0[g * 4 + 3]);
                    pk[0][g][0] = pack2(p0, p1);
                    pk[0][g][1] = pack2(p2, p3);
                }
                {
                    float p0 = __builtin_amdgcn_exp2f(z1[g * 4 + 0]);
                    float p1 = __builtin_amdgcn_exp2f(z1[g * 4 + 1]);
                    float p2 = __builtin_amdgcn_exp2f(z1[g * 4 + 2]);
                    float p3 = __builtin_amdgcn_exp2f(z1[g * 4 + 3]);
                    pk[1][g][0] = pack2(p0, p1);
                    pk[1][g][1] = pack2(p2, p3);
                }
            }

#pragma unroll
            for (int half = 0; half < 2; ++half) {
                const int c = t * 2 + half, G = half * 2;
                u32x4 fu0 = {pk[0][G][0], pk[0][G][1], pk[0][G + 1][0], pk[0][G + 1][1]};
                u32x4 fu1 = {pk[1][G][0], pk[1][G][1], pk[1][G + 1][0], pk[1][G + 1][1]};
                bf16x8 pf0 = __builtin_bit_cast(bf16x8, fu0);
                bf16x8 pf1 = __builtin_bit_cast(bf16x8, fu1);
                __builtin_amdgcn_s_setprio(1);
#pragma unroll
                for (int dt = 0; dt < 2; ++dt) {
                    const int swd = ((l31 ^ ((l31 >> 3) + dt * 4)) & 7) << 3;
                    bf16x8 vb = ldfrag(&Vl[p][dt * 32 + l31][(c * 16 + hi * 8) ^ swd]);
                    o[0][dt] = __builtin_amdgcn_mfma_f32_32x32x16_bf16(pf0, vb, o[0][dt], 0, 0, 0);
                    o[1][dt] = __builtin_amdgcn_mfma_f32_32x32x16_bf16(pf1, vb, o[1][dt], 0, 0, 0);
                }
                os[0] = __builtin_amdgcn_mfma_f32_32x32x16_bf16(pf0, vones, os[0], 0, 0, 0);
                os[1] = __builtin_amdgcn_mfma_f32_32x32x16_bf16(pf1, vones, os[1], 0, 0, 0);
                __builtin_amdgcn_s_setprio(0);
            }
        }

        if (kb + 128 < 2048 && tid < 128)
            mlb[p ^ 1][tid] = f2bf(mpre == 0 ? -30000.0f : 0.0f);
        __syncthreads();
    }

#pragma unroll
    for (int a = 0; a < 2; ++a)
#pragma unroll
        for (int g = 0; g < 4; ++g)
#pragma unroll
            for (int j = 0; j < 4; ++j) {
                const float inv = 1.0f / os[a][g * 4 + j];
                const size_t row = rowbase + q0 + w * 64 + a * 32 + g * 8 + hi * 4 + j;
                const int key = (int)((row >> 1) & 3);
                const int l31s = (l31 & 7) | ((((l31 >> 3) ^ key) & 3) << 3);
#pragma unroll
                for (int dt = 0; dt < 2; ++dt)
                    O[row * 1024 + hoff + dt * 32 + l31s] = f2bf(o[a][dt][g * 4 + j] * inv);
            }
}

// In-place LayerNorm over last dim (1024), one row per block.
__global__ __launch_bounds__(256) void ln_inplace(
    float* __restrict__ X, const float* __restrict__ gamma, const float* __restrict__ beta)
{
    __shared__ float red[8];
    const int tid = threadIdx.x, lane = tid & 63, w = tid >> 6;
    float* p = X + (size_t)blockIdx.x * 1024;
    f32x4 v = *((const f32x4*)p + tid);
    float s = v[0] + v[1] + v[2] + v[3];
    float s2 = v[0] * v[0] + v[1] * v[1] + v[2] * v[2] + v[3] * v[3];
#pragma unroll
    for (int d = 1; d < 64; d <<= 1) {
        s += __shfl_xor(s, d);
        s2 += __shfl_xor(s2, d);
    }
    if (lane == 0) { red[w] = s; red[4 + w] = s2; }
    __syncthreads();
    s = red[0] + red[1] + red[2] + red[3];
    s2 = red[4] + red[5] + red[6] + red[7];
    const float mu = s * (1.0f / 1024.0f);
    const float var = s2 * (1.0f / 1024.0f) - mu * mu;
    const float rstd = rsqrtf(var + 1e-5f);
    f32x4 g = *((const f32x4*)gamma + tid);
    f32x4 be = *((const f32x4*)beta + tid);
    f32x4 out;
#pragma unroll
    for (int j = 0; j < 4; ++j) out[j] = (v[j] - mu) * rstd * g[j] + be[j];
    *((f32x4*)p + tid) = out;
}

extern "C" void kernel_launch(void* const* d_in, const int* in_sizes, int n_in,
                              void* d_out, int out_size, void* d_ws, size_t ws_size,
                              hipStream_t stream) {
    const float* query = (const float*)d_in[0];
    const float* key_  = (const float*)d_in[1];
    const float* value = (const float*)d_in[2];
    const int*   mask  = (const int*)d_in[3];
    const float* Wq = (const float*)d_in[4];
    const float* bq = (const float*)d_in[5];
    const float* Wk = (const float*)d_in[6];
    const float* bk = (const float*)d_in[7];
    const float* Wv = (const float*)d_in[8];
    const float* bv = (const float*)d_in[9];
    const float* Wo = (const float*)d_in[10];
    const float* bo = (const float*)d_in[11];
    const float* gamma = (const float*)d_in[12];
    const float* beta  = (const float*)d_in[13];

    const size_t MD = (size_t)8192 * 1024;
    unsigned short* Qb  = (unsigned short*)d_ws;
    unsigned short* Kb  = Qb + MD;   // pre-swizzled K (per-head dh XOR g(token&127))
    unsigned short* Vtb = Kb + MD;   // V^T perm23 + swizzle: [b*16+h][dh][pos]
    unsigned short* Ab  = Vtb + MD;  // attn output (bf16, slot-swizzled)
    float* out = (float*)d_out;
    unsigned short* W16 = (unsigned short*)d_out;   // bf16 Wq/Wk/Wv (swizzled)
    unsigned short* Wo16 = Vtb;                     // after attn, Vtb is free

    const float qscale = 0.125f * 1.4426950408889634f;  // 1/sqrt(64) * log2(e)

    cvt_w3<<<dim3(512, 3), 256, 0, stream>>>(Wq, Wk, Wv, W16);
    gemm_qkv<<<dim3(64, 4, 3), 256, 0, stream>>>(
        query, key_, value, W16, bq, bk, bv, Qb, Kb, Vtb, qscale);

    attn_fwd<<<dim3(8, 64), 256, 0, stream>>>(Kb, Qb, Vtb, mask, Ab);

    cvt_w1<<<512, 256, 0, stream>>>(Wo, Wo16);
    gemm_out<<<dim3(64, 8), 256, 0, stream>>>(Ab, Wo16, bo, query, out);
    ln_inplace<<<8192, 256, 0, stream>>>(out, gamma, beta);
}

// Round 20
// 228.681 us; speedup vs baseline: 1.1467x; 1.1467x over previous
//
#include <hip/hip_runtime.h>
#include <hip/hip_bf16.h>

typedef __attribute__((ext_vector_type(4))) float f32x4;
typedef __attribute__((ext_vector_type(16))) float f32x16;
typedef __attribute__((ext_vector_type(2))) unsigned int u32x2;
typedef __attribute__((ext_vector_type(4))) unsigned int u32x4;
typedef __attribute__((ext_vector_type(8))) __bf16 bf16x8;

__device__ inline unsigned short f2bf(float x) {
    return __builtin_bit_cast(unsigned short, (__bf16)x);
}
__device__ inline unsigned int pack2(float lo, float hi) {
    return (unsigned int)f2bf(lo) | ((unsigned int)f2bf(hi) << 16);
}
__device__ inline u32x4 cvt8(const float* __restrict__ p) {
    f32x4 a = *(const f32x4*)p;
    f32x4 b = *(const f32x4*)(p + 4);
    u32x4 r;
    r[0] = pack2(a[0], a[1]);
    r[1] = pack2(a[2], a[3]);
    r[2] = pack2(b[0], b[1]);
    r[3] = pack2(b[2], b[3]);
    return r;
}
__device__ inline bf16x8 ldfrag(const unsigned short* p) {
    u32x4 t = *(const u32x4*)p;
    return __builtin_bit_cast(bf16x8, t);
}

// ---------------- fp32 -> bf16 weight converters, SLOT-SWIZZLED ----------
__global__ __launch_bounds__(256) void cvt_w3(
    const float* __restrict__ wq, const float* __restrict__ wk,
    const float* __restrict__ wv, unsigned short* __restrict__ dst)
{
    const float* s = blockIdx.y == 0 ? wq : (blockIdx.y == 1 ? wk : wv);
    unsigned short* d = dst + (size_t)blockIdx.y * 1048576;
    const int i = blockIdx.x * 256 + threadIdx.x;
    const int n = i >> 7;
    const int kg = (i >> 2) & 31;
    const int slot = (i & 3) ^ ((n >> 1) & 3);
    *(u32x4*)(d + (((size_t)n << 10) | (kg << 5) | (slot << 3))) =
        cvt8(s + (size_t)i * 8);
}
__global__ __launch_bounds__(256) void cvt_w1(
    const float* __restrict__ src, unsigned short* __restrict__ dst)
{
    const int i = blockIdx.x * 256 + threadIdx.x;
    const int n = i >> 7;
    const int kg = (i >> 2) & 31;
    const int slot = (i & 3) ^ ((n >> 1) & 3);
    *(u32x4*)(dst + (((size_t)n << 10) | (kg << 5) | (slot << 3))) =
        cvt8(src + (size_t)i * 8);
}

// ---------------- Fused QKV projection GEMM (r17 config) ----------------
// 128x128 tile, grid (64,8,3) z slowest; distance-4 A register prefetch;
// B linear-staged from pre-swizzled W16, fragment reads at slot fq^((fr>>1)&3).
// r20 nudge: A refill issued BEFORE the barrier (slot already consumed).
// z=0 -> Qb (alpha=qscale); z=1 -> Kb PRE-SWIZZLED (col^g(token&127),
// g(r)=((r^(r>>3))&7)<<3); z=2 -> Vtb [bh][dh][perm23(key)^g(dh&63)].
__global__ __launch_bounds__(256) void gemm_qkv(
    const float* __restrict__ Aq, const float* __restrict__ Ak,
    const float* __restrict__ Av, const unsigned short* __restrict__ W16,
    const float* __restrict__ bq, const float* __restrict__ bk,
    const float* __restrict__ bv, unsigned short* __restrict__ Qb,
    unsigned short* __restrict__ Kb, unsigned short* __restrict__ Vtb,
    float qscale)
{
    __shared__ unsigned short Al[2][128][40];
    __shared__ unsigned short Bl[2][128][32];
    const int z = blockIdx.z;
    const float* Ap = z == 0 ? Aq : (z == 1 ? Ak : Av);
    const unsigned short* Bw = W16 + (size_t)z * 1048576;
    const float* bias = z == 0 ? bq : (z == 1 ? bk : bv);
    const float alpha = z == 0 ? qscale : 1.0f;

    const int tid = threadIdx.x;
    const int lane = tid & 63, w = tid >> 6;
    const int wr = w >> 1, wc = w & 1;
    const int m0 = blockIdx.x * 128, n0 = blockIdx.y * 128;
    const int fr = lane & 15, fq = lane >> 4;
    const int fqs = (fq ^ ((fr >> 1) & 3)) * 8;

    f32x4 acc[4][4] = {};
    f32x4 apA[2][2], apB[2][2], apC[2][2], apD[2][2];   // distance-4 slots

    auto issueB = [&](int p, int k0) {
#pragma unroll
        for (int j = 0; j < 2; ++j) {
            const int f = (w * 2 + j) * 512 + lane * 8;
            const int r = f >> 5, c = f & 31;
            __builtin_amdgcn_global_load_lds(
                (const __attribute__((address_space(1))) void*)(Bw + (size_t)(n0 + r) * 1024 + k0 + c),
                (__attribute__((address_space(3))) void*)(&Bl[p][0][0] + (w * 2 + j) * 512),
                16, 0, 0);
        }
    };
    auto loadA = [&](f32x4 (&ap)[2][2], int k0) {
#pragma unroll
        for (int i = 0; i < 2; ++i) {
            const int e = (i * 256 + tid) * 8;
            const int r = e >> 5, c = e & 31;
            const float* src = Ap + (size_t)(m0 + r) * 1024 + k0 + c;
            ap[i][0] = *(const f32x4*)src;
            ap[i][1] = *(const f32x4*)(src + 4);
        }
    };
    auto stepBody = [&](int k0, f32x4 (&ap)[2][2], int p) {
        // convert slot (loaded 4 steps ago) -> LDS buf p
#pragma unroll
        for (int i = 0; i < 2; ++i) {
            const int e = (i * 256 + tid) * 8;
            const int r = e >> 5, c = e & 31;
            u32x4 v;
            v[0] = pack2(ap[i][0][0], ap[i][0][1]);
            v[1] = pack2(ap[i][0][2], ap[i][0][3]);
            v[2] = pack2(ap[i][1][0], ap[i][1][1]);
            v[3] = pack2(ap[i][1][2], ap[i][1][3]);
            *(u32x4*)&Al[p][r][c] = v;
        }
        if (k0 + 128 < 1024) loadA(ap, k0 + 128);   // refill early (pre-barrier)
        __syncthreads();
        if (k0 + 32 < 1024) issueB(p ^ 1, k0 + 32);

        bf16x8 af[4], bfv[4];
#pragma unroll
        for (int mt = 0; mt < 4; ++mt)
            af[mt] = ldfrag(&Al[p][wr * 64 + mt * 16 + fr][8 * fq]);
#pragma unroll
        for (int nt = 0; nt < 4; ++nt)
            bfv[nt] = ldfrag(&Bl[p][wc * 64 + nt * 16 + fr][fqs]);
#pragma unroll
        for (int mt = 0; mt < 4; ++mt)
#pragma unroll
            for (int nt = 0; nt < 4; ++nt)
                acc[mt][nt] = __builtin_amdgcn_mfma_f32_16x16x32_bf16(af[mt], bfv[nt], acc[mt][nt], 0, 0, 0);
    };

    loadA(apA, 0);
    loadA(apB, 32);
    loadA(apC, 64);
    loadA(apD, 96);
    issueB(0, 0);

    for (int k0 = 0; k0 < 1024; k0 += 128) {
        stepBody(k0 +  0, apA, 0);
        stepBody(k0 + 32, apB, 1);
        stepBody(k0 + 64, apC, 0);
        stepBody(k0 + 96, apD, 1);
    }

#pragma unroll
    for (int mt = 0; mt < 4; ++mt) {
#pragma unroll
        for (int nt = 0; nt < 4; ++nt) {
            const int col = n0 + wc * 64 + nt * 16 + fr;
            const float bb = bias[col];
            const int row0 = m0 + wr * 64 + mt * 16 + fq * 4;
            if (z == 2) {
                float v0 = acc[mt][nt][0] + bb, v1 = acc[mt][nt][1] + bb;
                float v2 = acc[mt][nt][2] + bb, v3 = acc[mt][nt][3] + bb;
                const int bb_ = row0 >> 11, key = row0 & 2047;
                const int key2 = (key & ~12) | ((key & 4) << 1) | ((key & 8) >> 1);
                const int dh = col & 63;
                const int gg = ((dh ^ (dh >> 3)) & 7) << 3;
                const size_t idx = ((size_t)bb_ * 1024 + col) * 2048 + (key2 ^ gg);
                u32x2 pv;
                pv[0] = pack2(v0, v1);
                pv[1] = pack2(v2, v3);
                *(u32x2*)(Vtb + idx) = pv;
            } else if (z == 1) {
#pragma unroll
                for (int r = 0; r < 4; ++r) {
                    const int row = row0 + r;
                    const int tm = row & 127;
                    const int gg = ((tm ^ (tm >> 3)) & 7) << 3;
                    const size_t idx = (size_t)row * 1024 + ((col & ~63) | ((col & 63) ^ gg));
                    Kb[idx] = f2bf(acc[mt][nt][r] + bb);
                }
            } else {
#pragma unroll
                for (int r = 0; r < 4; ++r) {
                    const size_t idx = (size_t)(row0 + r) * 1024 + col;
                    Qb[idx] = f2bf((acc[mt][nt][r] + bb) * alpha);
                }
            }
        }
    }
}

// ---------------- Output-projection GEMM (r15/r17, unchanged) -------
__global__ __launch_bounds__(256) void gemm_out(
    const unsigned short* __restrict__ A, const unsigned short* __restrict__ Bw,
    const float* __restrict__ bias, const float* __restrict__ resid,
    float* __restrict__ Cp)
{
    __shared__ unsigned short Al[2][128][32];
    __shared__ unsigned short Bl[2][128][32];
    const int tid = threadIdx.x;
    const int lane = tid & 63, w = tid >> 6;
    const int wr = w >> 1, wc = w & 1;
    const int m0 = blockIdx.x * 128, n0 = blockIdx.y * 128;
    const int fr = lane & 15, fq = lane >> 4;
    const int fqs = (fq ^ ((fr >> 1) & 3)) * 8;

    f32x4 acc[4][4] = {};

    auto stage = [&](int p, int k0) {
#pragma unroll
        for (int j = 0; j < 2; ++j) {
            const int f = (w * 2 + j) * 512 + lane * 8;
            const int r = f >> 5, c = f & 31;
            __builtin_amdgcn_global_load_lds(
                (const __attribute__((address_space(1))) void*)(A + (size_t)(m0 + r) * 1024 + k0 + c),
                (__attribute__((address_space(3))) void*)(&Al[p][0][0] + (w * 2 + j) * 512),
                16, 0, 0);
            __builtin_amdgcn_global_load_lds(
                (const __attribute__((address_space(1))) void*)(Bw + (size_t)(n0 + r) * 1024 + k0 + c),
                (__attribute__((address_space(3))) void*)(&Bl[p][0][0] + (w * 2 + j) * 512),
                16, 0, 0);
        }
    };

    stage(0, 0);

    for (int k0 = 0; k0 < 1024; k0 += 32) {
        const int p = (k0 >> 5) & 1;
        __syncthreads();
        if (k0 + 32 < 1024) stage(p ^ 1, k0 + 32);

        bf16x8 af[4], bfv[4];
#pragma unroll
        for (int mt = 0; mt < 4; ++mt)
            af[mt] = ldfrag(&Al[p][wr * 64 + mt * 16 + fr][fqs]);
#pragma unroll
        for (int nt = 0; nt < 4; ++nt)
            bfv[nt] = ldfrag(&Bl[p][wc * 64 + nt * 16 + fr][fqs]);
#pragma unroll
        for (int mt = 0; mt < 4; ++mt)
#pragma unroll
            for (int nt = 0; nt < 4; ++nt)
                acc[mt][nt] = __builtin_amdgcn_mfma_f32_16x16x32_bf16(af[mt], bfv[nt], acc[mt][nt], 0, 0, 0);
    }

#pragma unroll
    for (int mt = 0; mt < 4; ++mt) {
#pragma unroll
        for (int nt = 0; nt < 4; ++nt) {
            const int col = n0 + wc * 64 + nt * 16 + fr;
            const float bb = bias[col];
            const int row0 = m0 + wr * 64 + mt * 16 + fq * 4;
#pragma unroll
            for (int r = 0; r < 4; ++r) {
                const size_t idx = (size_t)(row0 + r) * 1024 + col;
                Cp[idx] = acc[mt][nt][r] + bb + resid[idx];
            }
        }
    }
}

// ---------------- Flash attention (r15/r17, unchanged) ----------------
__global__ __launch_bounds__(256, 2) void attn_fwd(
    const unsigned short* __restrict__ K, const unsigned short* __restrict__ Q,
    const unsigned short* __restrict__ Vt_g, const int* __restrict__ mask,
    unsigned short* __restrict__ O)
{
    __shared__ unsigned short Kl[2][128][64];
    __shared__ unsigned short Vl[2][64][128];
    __shared__ unsigned short mlb[2][128];
    const int tid = threadIdx.x, lane = tid & 63, w = tid >> 6;
    const int l31 = lane & 31, hi = lane >> 5;
    const int qb = blockIdx.y >> 3;
    const int bh = ((blockIdx.y & 7) << 3) | blockIdx.x;
    const int q0 = qb * 256;
    const int b = bh >> 4;
    const size_t rowbase = (size_t)b * 2048;
    const int hoff = (bh & 15) * 64;
    const size_t vbase = (size_t)bh * 64 * 2048;

    const u32x4 onesu = {0x3F803F80u, 0x3F803F80u, 0x3F803F80u, 0x3F803F80u};
    const bf16x8 vones = __builtin_bit_cast(bf16x8, onesu);

    bf16x8 aq[2][4];
#pragma unroll
    for (int a = 0; a < 2; ++a) {
        const unsigned short* qp = Q + (rowbase + q0 + w * 64 + a * 32 + l31) * 1024 + hoff + hi * 8;
#pragma unroll
        for (int kk = 0; kk < 4; ++kk) aq[a][kk] = ldfrag(qp + kk * 16);
    }
    f32x16 o[2][2] = {};
    f32x16 os[2] = {};

    auto stageKV = [&](int p, int kb2) {
#pragma unroll
        for (int j = 0; j < 4; ++j) {
            const int q = w * 4 + j;
            const int hK = q * 512 + lane * 8;
            const int rK = hK >> 6, cK = hK & 63;
            __builtin_amdgcn_global_load_lds(
                (const __attribute__((address_space(1))) void*)(K + (rowbase + kb2 + rK) * 1024 + hoff + cK),
                (__attribute__((address_space(3))) void*)(&Kl[p][0][0] + q * 512),
                16, 0, 0);
            const int rV = hK >> 7, cV = hK & 127;
            __builtin_amdgcn_global_load_lds(
                (const __attribute__((address_space(1))) void*)(Vt_g + vbase + (size_t)rV * 2048 + kb2 + cV),
                (__attribute__((address_space(3))) void*)(&Vl[p][0][0] + q * 512),
                16, 0, 0);
        }
    };

    stageKV(0, 0);
    int mpre = (tid < 128) ? mask[rowbase + tid] : 0;
    if (tid < 128) mlb[0][tid] = f2bf(mpre == 0 ? -30000.0f : 0.0f);
    __syncthreads();

    for (int kb = 0, it = 0; kb < 2048; kb += 128, ++it) {
        const int p = it & 1;
        if (kb + 128 < 2048) {
            stageKV(p ^ 1, kb + 128);
            if (tid < 128) mpre = mask[rowbase + kb + 128 + tid];
        }

#pragma unroll
        for (int t = 0; t < 4; ++t) {
            const int swt = ((l31 ^ ((l31 >> 3) + t * 4)) & 7) << 3;
            const unsigned int mv = (hi == 0) ? (unsigned int)mlb[p][t * 32 + l31] : 0u;
            const u32x4 mfu = {mv, 0u, 0u, 0u};
            const bf16x8 kfm = __builtin_bit_cast(bf16x8, mfu);

            f32x16 z0 = {}, z1 = {};
            __builtin_amdgcn_s_setprio(1);
            z0 = __builtin_amdgcn_mfma_f32_32x32x16_bf16(kfm, vones, z0, 0, 0, 0);
            z1 = __builtin_amdgcn_mfma_f32_32x32x16_bf16(kfm, vones, z1, 0, 0, 0);
#pragma unroll
            for (int kk = 0; kk < 4; ++kk) {
                bf16x8 kf = ldfrag(&Kl[p][t * 32 + l31][(kk * 16 + hi * 8) ^ swt]);
                z0 = __builtin_amdgcn_mfma_f32_32x32x16_bf16(kf, aq[0][kk], z0, 0, 0, 0);
                z1 = __builtin_amdgcn_mfma_f32_32x32x16_bf16(kf, aq[1][kk], z1, 0, 0, 0);
            }
            __builtin_amdgcn_s_setprio(0);

            unsigned int pk[2][4][2];
#pragma unroll
            for (int g = 0; g < 4; ++g) {
                {
                    float p0 = __builtin_amdgcn_exp2f(z0[g * 4 + 0]);
                    float p1 = __builtin_amdgcn_exp2f(z0[g * 4 + 1]);
                    float p2 = __builtin_amdgcn_exp2f(z0[g * 4 + 2]);
                    float p3 = __builtin_amdgcn_exp2f(z0[g * 4 + 3]);
                    pk[0][g][0] = pack2(p0, p1);
                    pk[0][g][1] = pack2(p2, p3);
                }
                {
                    float p0 = __builtin_amdgcn_exp2f(z1[g * 4 + 0]);
                    float p1 = __builtin_amdgcn_exp2f(z1[g * 4 + 1]);
                    float p2 = __builtin_amdgcn_exp2f(z1[g * 4 + 2]);
                    float p3 = __builtin_amdgcn_exp2f(z1[g * 4 + 3]);
                    pk[1][g][0] = pack2(p0, p1);
                    pk[1][g][1] = pack2(p2, p3);
                }
            }

#pragma unroll
            for (int half = 0; half < 2; ++half) {
                const int c = t * 2 + half, G = half * 2;
                u32x4 fu0 = {pk[0][G][0], pk[0][G][1], pk[0][G + 1][0], pk[0][G + 1][1]};
                u32x4 fu1 = {pk[1][G][0], pk[1][G][1], pk[1][G + 1][0], pk[1][G + 1][1]};
                bf16x8 pf0 = __builtin_bit_cast(bf16x8, fu0);
                bf16x8 pf1 = __builtin_bit_cast(bf16x8, fu1);
                __builtin_amdgcn_s_setprio(1);
#pragma unroll
                for (int dt = 0; dt < 2; ++dt) {
                    const int swd = ((l31 ^ ((l31 >> 3) + dt * 4)) & 7) << 3;
                    bf16x8 vb = ldfrag(&Vl[p][dt * 32 + l31][(c * 16 + hi * 8) ^ swd]);
                    o[0][dt] = __builtin_amdgcn_mfma_f32_32x32x16_bf16(pf0, vb, o[0][dt], 0, 0, 0);
                    o[1][dt] = __builtin_amdgcn_mfma_f32_32x32x16_bf16(pf1, vb, o[1][dt], 0, 0, 0);
                }
                os[0] = __builtin_amdgcn_mfma_f32_32x32x16_bf16(pf0, vones, os[0], 0, 0, 0);
                os[1] = __builtin_amdgcn_mfma_f32_32x32x16_bf16(pf1, vones, os[1], 0, 0, 0);
                __builtin_amdgcn_s_setprio(0);
            }
        }

        if (kb + 128 < 2048 && tid < 128)
            mlb[p ^ 1][tid] = f2bf(mpre == 0 ? -30000.0f : 0.0f);
        __syncthreads();
    }

#pragma unroll
    for (int a = 0; a < 2; ++a)
#pragma unroll
        for (int g = 0; g < 4; ++g)
#pragma unroll
            for (int j = 0; j < 4; ++j) {
                const float inv = 1.0f / os[a][g * 4 + j];
                const size_t row = rowbase + q0 + w * 64 + a * 32 + g * 8 + hi * 4 + j;
                const int key = (int)((row >> 1) & 3);
                const int l31s = (l31 & 7) | ((((l31 >> 3) ^ key) & 3) << 3);
#pragma unroll
                for (int dt = 0; dt < 2; ++dt)
                    O[row * 1024 + hoff + dt * 32 + l31s] = f2bf(o[a][dt][g * 4 + j] * inv);
            }
}

// In-place LayerNorm over last dim (1024), one row per block.
__global__ __launch_bounds__(256) void ln_inplace(
    float* __restrict__ X, const float* __restrict__ gamma, const float* __restrict__ beta)
{
    __shared__ float red[8];
    const int tid = threadIdx.x, lane = tid & 63, w = tid >> 6;
    float* p = X + (size_t)blockIdx.x * 1024;
    f32x4 v = *((const f32x4*)p + tid);
    float s = v[0] + v[1] + v[2] + v[3];
    float s2 = v[0] * v[0] + v[1] * v[1] + v[2] * v[2] + v[3] * v[3];
#pragma unroll
    for (int d = 1; d < 64; d <<= 1) {
        s += __shfl_xor(s, d);
        s2 += __shfl_xor(s2, d);
    }
    if (lane == 0) { red[w] = s; red[4 + w] = s2; }
    __syncthreads();
    s = red[0] + red[1] + red[2] + red[3];
    s2 = red[4] + red[5] + red[6] + red[7];
    const float mu = s * (1.0f / 1024.0f);
    const float var = s2 * (1.0f / 1024.0f) - mu * mu;
    const float rstd = rsqrtf(var + 1e-5f);
    f32x4 g = *((const f32x4*)gamma + tid);
    f32x4 be = *((const f32x4*)beta + tid);
    f32x4 out;
#pragma unroll
    for (int j = 0; j < 4; ++j) out[j] = (v[j] - mu) * rstd * g[j] + be[j];
    *((f32x4*)p + tid) = out;
}

extern "C" void kernel_launch(void* const* d_in, const int* in_sizes, int n_in,
                              void* d_out, int out_size, void* d_ws, size_t ws_size,
                              hipStream_t stream) {
    const float* query = (const float*)d_in[0];
    const float* key_  = (const float*)d_in[1];
    const float* value = (const float*)d_in[2];
    const int*   mask  = (const int*)d_in[3];
    const float* Wq = (const float*)d_in[4];
    const float* bq = (const float*)d_in[5];
    const float* Wk = (const float*)d_in[6];
    const float* bk = (const float*)d_in[7];
    const float* Wv = (const float*)d_in[8];
    const float* bv = (const float*)d_in[9];
    const float* Wo = (const float*)d_in[10];
    const float* bo = (const float*)d_in[11];
    const float* gamma = (const float*)d_in[12];
    const float* beta  = (const float*)d_in[13];

    const size_t MD = (size_t)8192 * 1024;
    unsigned short* Qb  = (unsigned short*)d_ws;
    unsigned short* Kb  = Qb + MD;   // pre-swizzled K (per-head dh XOR g(token&127))
    unsigned short* Vtb = Kb + MD;   // V^T perm23 + swizzle: [b*16+h][dh][pos]
    unsigned short* Ab  = Vtb + MD;  // attn output (bf16, slot-swizzled)
    float* out = (float*)d_out;
    unsigned short* W16 = (unsigned short*)d_out;   // bf16 Wq/Wk/Wv (swizzled)
    unsigned short* Wo16 = Vtb;                     // after attn, Vtb is free

    const float qscale = 0.125f * 1.4426950408889634f;  // 1/sqrt(64) * log2(e)

    cvt_w3<<<dim3(512, 3), 256, 0, stream>>>(Wq, Wk, Wv, W16);
    gemm_qkv<<<dim3(64, 8, 3), 256, 0, stream>>>(
        query, key_, value, W16, bq, bk, bv, Qb, Kb, Vtb, qscale);

    attn_fwd<<<dim3(8, 64), 256, 0, stream>>>(Kb, Qb, Vtb, mask, Ab);

    cvt_w1<<<512, 256, 0, stream>>>(Wo, Wo16);
    gemm_out<<<dim3(64, 8), 256, 0, stream>>>(Ab, Wo16, bo, query, out);
    ln_inplace<<<8192, 256, 0, stream>>>(out, gamma, beta);
}